// Round 8
// baseline (24606.146 us; speedup 1.0000x reference)
//
#include <hip/hip_runtime.h>

#define TSEQ 2048
#define NB   20
#define NIN  256
#define NH   512
#define NOUT 128

typedef unsigned int   u32;
typedef unsigned short u16;
typedef _Float16 f16x2 __attribute__((ext_vector_type(2)));

// dynamic LDS layout
#define SM_W     0                 // 131072 B: WL uint2[32][512] (pre1 only now)
#define SM_HX    131072            // 2048 B: h exchange, TWO sigma-swizzled f16[512] buffers
#define SM_INP   (131072 + 2048)   // 2048 B: u32 [2][256] input staging (pre roles)
#define SMEM_BYTES (131072 + 2048 + 2048)

__device__ __forceinline__ u32 packh2(float a, float b) {
  f16x2 p; p.x = (_Float16)a; p.y = (_Float16)b;
  return __builtin_bit_cast(u32, p);
}

__device__ __forceinline__ float dot2(u32 w, u32 h, float acc) {
  return __builtin_amdgcn_fdot2(__builtin_bit_cast(f16x2, w),
                                __builtin_bit_cast(f16x2, h), acc, false);
}

__device__ __forceinline__ int acq(const int* p) {
  return __hip_atomic_load(p, __ATOMIC_ACQUIRE, __HIP_MEMORY_SCOPE_AGENT);
}
__device__ __forceinline__ void rel(int* p, int v) {
  __hip_atomic_store(p, v, __ATOMIC_RELEASE, __HIP_MEMORY_SCOPE_AGENT);
}
// spin with s_sleep backoff
__device__ __forceinline__ void spin_until(const int* p, int need, int& seen) {
  while (seen < need) {
    seen = acq(p);
    if (seen < need) __builtin_amdgcn_s_sleep(1);
  }
}

// LDS-only barrier: orders LDS ops across the workgroup WITHOUT draining vmcnt.
// Also a memory clobber -> prevents LICM of the per-step global slab loads.
__device__ __forceinline__ void lds_barrier() {
  asm volatile("s_waitcnt lgkmcnt(0)\n\ts_barrier" ::: "memory");
}

// cross-lane add via DPP (VALU pipe, no LDS).
// 0xB1 quad_perm[1,0,3,2]=xor1, 0x4E quad_perm[2,3,0,1]=xor2,
// 0x124 row_ror:4, 0x128 row_ror:8 (rows are 16 lanes on gfx9+)
template<int CTRL>
__device__ __forceinline__ float dpp_add(float x) {
  int v = __builtin_amdgcn_update_dpp(0, __builtin_bit_cast(int, x), CTRL, 0xF, 0xF, true);
  return x + __builtin_bit_cast(float, v);
}

template<int CTRL>
__device__ __forceinline__ u32 dpp_mov_u32(u32 x) {
  return (u32)__builtin_amdgcn_update_dpp(0, (int)x, CTRL, 0xF, 0xF, true);
}

__device__ __forceinline__ float fast_tanh(float x) {
  float xc = fminf(fmaxf(x, -15.f), 15.f);
  float e = __builtin_amdgcn_exp2f(xc * 2.8853900817779268f);  // exp(2x)
  return (e - 1.f) * __builtin_amdgcn_rcpf(e + 1.f);
}

// sigma-swizzle for hx (verified rounds 4-7: SQ_LDS_BANK_CONFLICT = 0)
__device__ __forceinline__ int hx_gran_off(int g, int c) {
  int pg = (g ^ (g >> 2)) & 15;
  return 64 * pg + 16 * (c ^ (g & 3));
}

// Persistent fused pipeline. grid = 160 blocks x 512 threads, 1 block/CU.
//  bid   0..39 : pre0 (b=bid>>1, half=bid&1)        pre0 = x@Wih0^T + bih0 (f16, 8-t tiles)
//  bid  40..59 : L0 recurrence (b=bid-40)           out0 = h packed f16 pairs
//  bid 60..139 : pre1 (b=(bid-60)>>2, sub=(bid-60)&3) 4-way t-chunked gather (8-t tiles)
//  bid140..159 : L1 recurrence (b=bid-140)          h1f = last h (f32)
//
// Overflow weight rows (4 of 16 per thread) live in a per-layer GLOBAL slab
// (L2-resident, 128 KB, written once by the b==0 block of each layer) instead
// of LDS: cuts recurrence LDS traffic ~4x (round-7 analysis: LDS slab re-read
// was ~1540 cyc/step, the top pipe).
__global__ __launch_bounds__(512, 2) void rnn_persist(
    const float* __restrict__ x,    const float* __restrict__ h0,
    const float* __restrict__ Wih0, const float* __restrict__ Whh0,
    const float* __restrict__ bih0, const float* __restrict__ bhh0,
    const float* __restrict__ Wih1, const float* __restrict__ Whh1,
    const float* __restrict__ bih1, const float* __restrict__ bhh1,
    u16* __restrict__ pre0, u32* __restrict__ out0,
    u16* __restrict__ pre1, float* __restrict__ h1f,
    int* __restrict__ flags, u32* __restrict__ gw)
{
  extern __shared__ char smem[];
  const int tid = threadIdx.x;
  const int bid = blockIdx.x;

  if (bid < 40) {
    // ---------------- pre0: x @ Wih0^T + bih0 (tiled store) ----------------
    u32* inp = (u32*)(smem + SM_INP);
    const int b = bid >> 1, half = bid & 1, t0 = half * 1024;
    const int n = tid;
    u32 wr[128];
    const float4* W4 = (const float4*)(Wih0 + (size_t)n * NIN);
#pragma unroll
    for (int j = 0; j < 64; j++) {
      float4 w = W4[j];
      wr[2*j] = packh2(w.x, w.y); wr[2*j+1] = packh2(w.z, w.w);
    }
    const float bias = bih0[n];
    const float* xb = x + ((size_t)b * TSEQ + t0) * NIN;
    u16* op = pre0 + ((size_t)b * TSEQ + t0) * NH;

    float2 r = make_float2(0.f, 0.f);
    if (tid < 128) r = ((const float2*)xb)[tid];
    int cur = 0;
    for (int t = 0; t < 1024; t++) {
      if (tid < 128) inp[cur * 256 + tid] = packh2(r.x, r.y);
      __syncthreads();
      if (t + 1 < 1024 && tid < 128)
        r = ((const float2*)(xb + (size_t)(t + 1) * NIN))[tid];
      float a0 = bias, a1 = 0.f;
      const uint4* xp = (const uint4*)(inp + cur * 256);
#pragma unroll
      for (int j = 0; j < 32; j++) {
        uint4 hv = xp[j];
        a0 = dot2(wr[4*j+0], hv.x, a0); a1 = dot2(wr[4*j+1], hv.y, a1);
        a0 = dot2(wr[4*j+2], hv.z, a0); a1 = dot2(wr[4*j+3], hv.w, a1);
      }
      op[((size_t)(t >> 3) * NH + n) * 8 + (t & 7)] =
          __builtin_bit_cast(u16, (_Float16)(a0 + a1));
      cur ^= 1;
      if (((t + 1) & 7) == 0) {
        __syncthreads();
        if (tid == 0) rel(flags + bid * 32, t + 1);
      }
    }
    return;
  }

  if (bid >= 60 && bid < 140) {
    // ---------------- pre1: out0 @ Wih1^T + bih1, 4-way t-chunk split ----------------
    uint2* WL  = (uint2*)(smem + SM_W);
    u32*   inp = (u32*)(smem + SM_INP);
    const int b = (bid - 60) >> 2, sub = (bid - 60) & 3;
    const int n = tid;
    u32 wr[192];
    const float4* W4 = (const float4*)(Wih1 + (size_t)n * NH);
#pragma unroll
    for (int j = 0; j < 96; j++) {
      float4 w = W4[j];
      wr[2*j] = packh2(w.x, w.y); wr[2*j+1] = packh2(w.z, w.w);
    }
#pragma unroll
    for (int j2 = 0; j2 < 32; j2++) {
      float4 w = W4[96 + j2];
      WL[j2 * NH + n] = make_uint2(packh2(w.x, w.y), packh2(w.z, w.w));
    }
    const float bias = bih1[n];
    __syncthreads();

    const u32* ip = out0 + (size_t)b * TSEQ * 256;
    u16* op = pre1 + (size_t)b * TSEQ * NH;
    const int* flagOut0 = flags + (40 + b) * 32;
    int* flagMy = flags + (60 + b * 4 + sub) * 32;
    int seen = 0, cur = 0;
#pragma unroll 1
    for (int c = sub; c < TSEQ / 8; c += 4) {
      const int tbase = c * 8;
      spin_until(flagOut0, tbase + 8, seen);
      u32 rin = (tid < 256) ? ip[(size_t)tbase * 256 + tid] : 0;
#pragma unroll 1
      for (int qq = 0; qq < 8; qq++) {
        const int t = tbase + qq;
        if (tid < 256) inp[cur * 256 + tid] = rin;
        __syncthreads();
        if (qq + 1 < 8 && tid < 256) rin = ip[(size_t)(t + 1) * 256 + tid];
        float a0 = bias, a1 = 0.f;
        const uint4* hp4 = (const uint4*)(inp + cur * 256);
#pragma unroll
        for (int j = 0; j < 48; j++) {
          uint4 hv = hp4[j];
          a0 = dot2(wr[4*j+0], hv.x, a0); a1 = dot2(wr[4*j+1], hv.y, a1);
          a0 = dot2(wr[4*j+2], hv.z, a0); a1 = dot2(wr[4*j+3], hv.w, a1);
        }
#pragma unroll
        for (int jj = 0; jj < 16; jj++) {
          uint4 hv = hp4[48 + jj];
          uint2 w0 = WL[(2*jj)   * NH + n];
          uint2 w1 = WL[(2*jj+1) * NH + n];
          a0 = dot2(w0.x, hv.x, a0); a1 = dot2(w0.y, hv.y, a1);
          a0 = dot2(w1.x, hv.z, a0); a1 = dot2(w1.y, hv.w, a1);
        }
        op[((size_t)(t >> 3) * NH + n) * 8 + (t & 7)] =
            __builtin_bit_cast(u16, (_Float16)(a0 + a1));
        cur ^= 1;
      }
      __syncthreads();
      if (tid == 0) rel(flagMy, tbase + 8);
    }
    return;
  }

  // ---------------- L0 / L1 recurrence: scatter + grouped DPP pairing tree ----------------
  const bool isL0 = (bid < 60);
  const int b = isL0 ? (bid - 40) : (bid - 140);
  const float* Wg = isL0 ? Whh0 : Whh1;
  const float* bp = isL0 ? bhh0 : bhh1;

  char* hxc = smem + SM_HX;             // 2x sigma-swizzled f16[512]
  // per-layer global weight slab (uint4 granules, slot layout [s][tid])
  uint4* GW4 = (uint4*)(gw + (isL0 ? 0 : 1) * 32768);
  int* slabF = flags + (200 + (isL0 ? 0 : 1)) * 32;

  const int lam = tid & 15;             // k-group: k in [32*lam, 32*lam+32)
  const int ns  = tid >> 4;             // n-slice: rows 16*ns .. 16*ns+15

  // Register rows: group g holds matrix rows 16*ns + {4g, 4g+1, 4g+2} in wj[3g+m].
  u32 wj[12][16];
#pragma unroll
  for (int g = 0; g < 4; g++) {
#pragma unroll
    for (int m = 0; m < 3; m++) {
      const float4* Wr = (const float4*)(Wg + (size_t)(16 * ns + 4 * g + m) * NH + 32 * lam);
#pragma unroll
      for (int k4 = 0; k4 < 8; k4++) {
        float4 w = Wr[k4];
        wj[3*g+m][2*k4] = packh2(w.x, w.y); wj[3*g+m][2*k4+1] = packh2(w.z, w.w);
      }
    }
  }
  // Overflow rows (16*ns + 4g+3): b==0 packs them once into the global slab.
  if (b == 0) {
#pragma unroll
    for (int g = 0; g < 4; g++) {
      const float4* Wr = (const float4*)(Wg + (size_t)(16 * ns + 4 * g + 3) * NH + 32 * lam);
#pragma unroll
      for (int q = 0; q < 4; q++) {
        float4 wA = Wr[2*q], wB = Wr[2*q+1];
        GW4[(4 * g + q) * 512 + tid] =
            make_uint4(packh2(wA.x, wA.y), packh2(wA.z, wA.w),
                       packh2(wB.x, wB.y), packh2(wB.z, wB.w));
      }
    }
  }
  const float bias = bp[tid];           // final owner n == tid

  // precomputed hx addresses (loop-invariant, static-indexed)
  int hadr[4];
#pragma unroll
  for (int c = 0; c < 4; c++) hadr[c] = hx_gran_off(lam, c);
  const int wg = (tid >> 5) & 15, wc = (tid >> 3) & 3;
  const int waddr = hx_gran_off(wg, wc) + (tid & 7) * 2;  // my h[tid] slot
  const bool b0 = (tid & 1), b1 = (tid & 2), b2 = (tid & 4), b3 = (tid & 8);

  // init h exchange buffer 0 with h0
  *(u16*)(hxc + waddr) =
      __builtin_bit_cast(u16, (_Float16)h0[((isL0 ? 0 : 1) * NB + b) * NH + tid]);
  __syncthreads();   // drains slab stores (vmcnt 0) + hx write
  if (b == 0 && tid == 0) rel(slabF, 1);
  { int sv = 0; spin_until(slabF, 1, sv); }  // slab visible via L2 after acquire

  const uint4* pin4 =
      (const uint4*)((isL0 ? pre0 : pre1) + (size_t)b * TSEQ * NH);
  u32* o0p = out0 + (size_t)b * TSEQ * 256;
  int* flagOut0 = flags + (40 + b) * 32;
  const int* f0 = flags + (b * 2 + 0) * 32;       // pre0 halves (L0)
  const int* f1 = flags + (b * 2 + 1) * 32;
  const int* fpA = flags + (60 + b * 4 + 0) * 32; // pre1 subs (L1)
  const int* fpB = flags + (60 + b * 4 + 1) * 32;
  const int* fpC = flags + (60 + b * 4 + 2) * 32;
  const int* fpD = flags + (60 + b * 4 + 3) * 32;
  int s0 = 0, s1 = 0, sA = 0, sB = 0, sC = 0, sD = 0;

  // prologue: fetch chunk 0 into pcur4, chunk 1 into pnext4
  if (isL0) { spin_until(f0, 8, s0); }  else { spin_until(fpA, 8, sA); }
  uint4 pcur4 = pin4[tid];
  if (isL0) { spin_until(f0, 16, s0); } else { spin_until(fpB, 16, sB); }
  uint4 pnext4 = pin4[512 + tid];

  // group gi: rows 4gi..4gi+2 from wj, row 4gi+3 from the L2 slab (4 dwordx4).
#define ROW16(acc, WR)                                              \
    acc = dot2(WR[0],  hv0.x, acc); acc = dot2(WR[1],  hv0.y, acc); \
    acc = dot2(WR[2],  hv0.z, acc); acc = dot2(WR[3],  hv0.w, acc); \
    acc = dot2(WR[4],  hv1.x, acc); acc = dot2(WR[5],  hv1.y, acc); \
    acc = dot2(WR[6],  hv1.z, acc); acc = dot2(WR[7],  hv1.w, acc); \
    acc = dot2(WR[8],  hv2.x, acc); acc = dot2(WR[9],  hv2.y, acc); \
    acc = dot2(WR[10], hv2.z, acc); acc = dot2(WR[11], hv2.w, acc); \
    acc = dot2(WR[12], hv3.x, acc); acc = dot2(WR[13], hv3.y, acc); \
    acc = dot2(WR[14], hv3.z, acc); acc = dot2(WR[15], hv3.w, acc)

#define GROUP(gi, OUT)                                               \
  {                                                                  \
    const uint4 wvA = GW4[(4*gi + 0) * 512 + tid];                   \
    const uint4 wvB = GW4[(4*gi + 1) * 512 + tid];                   \
    const uint4 wvC = GW4[(4*gi + 2) * 512 + tid];                   \
    const uint4 wvD = GW4[(4*gi + 3) * 512 + tid];                   \
    float a0 = 0.f, a1 = 0.f, a2 = 0.f, a3 = 0.f;                    \
    ROW16(a0, wj[3*gi+0]);                                           \
    ROW16(a1, wj[3*gi+1]);                                           \
    ROW16(a2, wj[3*gi+2]);                                           \
    a3 = dot2(wvA.x, hv0.x, a3); a3 = dot2(wvA.y, hv0.y, a3);        \
    a3 = dot2(wvA.z, hv0.z, a3); a3 = dot2(wvA.w, hv0.w, a3);        \
    a3 = dot2(wvB.x, hv1.x, a3); a3 = dot2(wvB.y, hv1.y, a3);        \
    a3 = dot2(wvB.z, hv1.z, a3); a3 = dot2(wvB.w, hv1.w, a3);        \
    a3 = dot2(wvC.x, hv2.x, a3); a3 = dot2(wvC.y, hv2.y, a3);        \
    a3 = dot2(wvC.z, hv2.z, a3); a3 = dot2(wvC.w, hv2.w, a3);        \
    a3 = dot2(wvD.x, hv3.x, a3); a3 = dot2(wvD.y, hv3.y, a3);        \
    a3 = dot2(wvD.z, hv3.z, a3); a3 = dot2(wvD.w, hv3.w, a3);        \
    float t0 = dpp_add<0xB1>(a0), t1 = dpp_add<0xB1>(a1);            \
    float t2 = dpp_add<0xB1>(a2), t3 = dpp_add<0xB1>(a3);            \
    float u0 = b0 ? t1 : t0, u1 = b0 ? t3 : t2;                      \
    u0 = dpp_add<0x4E>(u0); u1 = dpp_add<0x4E>(u1);                  \
    OUT = b1 ? u1 : u0;                                              \
  }

  float hlast = 0.f;
#pragma unroll 1
  for (int c = 0; c < TSEQ / 8; c++) {
#pragma unroll 1
    for (int q = 0; q < 8; q++) {
      const int t = c * 8 + q;
      const int rbase = (t & 1) << 10;   // read buffer
      const int wbase = rbase ^ 1024;    // write buffer

      const uint4 hv0 = *(const uint4*)(hxc + rbase + hadr[0]);
      const uint4 hv1 = *(const uint4*)(hxc + rbase + hadr[1]);
      const uint4 hv2 = *(const uint4*)(hxc + rbase + hadr[2]);
      const uint4 hv3 = *(const uint4*)(hxc + rbase + hadr[3]);

      float G0, G1, G2, G3;
      GROUP(0, G0); GROUP(1, G1); GROUP(2, G2); GROUP(3, G3);
      G0 = dpp_add<0x124>(G0); G1 = dpp_add<0x124>(G1);
      G2 = dpp_add<0x124>(G2); G3 = dpp_add<0x124>(G3);
      float r0 = b2 ? G1 : G0, r1 = b2 ? G3 : G2;
      r0 = dpp_add<0x128>(r0); r1 = dpp_add<0x128>(r1);
      const float red = b3 ? r1 : r0;

      // extract pre-activation q from pcur4 (selects only, no array indexing)
      const u32 wlo  = (q & 4) ? pcur4.z : pcur4.x;
      const u32 whi  = (q & 4) ? pcur4.w : pcur4.y;
      const u32 wsel = (q & 2) ? whi : wlo;
      const u16 pq   = (u16)((q & 1) ? (wsel >> 16) : (wsel & 0xffffu));

      const float h = fast_tanh(red + bias + (float)__builtin_bit_cast(_Float16, pq));
      hlast = h;
      const u16 h16 = __builtin_bit_cast(u16, (_Float16)h);
      *(u16*)(hxc + wbase + waddr) = h16;

      if (isL0) {
        // pack (h[2k], h[2k+1]) via DPP xor1 and store from even lanes
        u32 v = (u32)h16;
        u32 nb = dpp_mov_u32<0xB1>(v);
        if (!(tid & 1)) o0p[(size_t)t * 256 + (tid >> 1)] = v | (nb << 16);
      }

      if (q == 7) __syncthreads();  // full drain (vm for flag release)
      else        lds_barrier();    // LDS-only ordering; vm ops stay in flight
    }

    if (isL0 && tid == 0) rel(flagOut0, c * 8 + 8);

    // rotate chunk buffers, prefetch chunk c+2
    pcur4 = pnext4;
    if (c < TSEQ / 8 - 2) {
      const int c2 = c + 2;
      const int need = 8 * (c2 + 1);
      if (isL0) {
        if (c2 < 128) { spin_until(f0, need, s0); }
        else          { spin_until(f1, need - 1024, s1); }
      } else {
        const int w = c2 & 3;
        if      (w == 0) { spin_until(fpA, need, sA); }
        else if (w == 1) { spin_until(fpB, need, sB); }
        else if (w == 2) { spin_until(fpC, need, sC); }
        else             { spin_until(fpD, need, sD); }
      }
      pnext4 = pin4[(size_t)c2 * 512 + tid];
    }
  }
#undef GROUP
#undef ROW16

  if (!isL0) h1f[(size_t)b * NH + tid] = hlast;
}

__global__ void fc_kernel(const float* __restrict__ h1f, const float* __restrict__ Wfc,
                          const float* __restrict__ bfc, float* __restrict__ out) {
  const int b = blockIdx.x, o = threadIdx.x;  // 20 blocks x 128 threads
  __shared__ float hs[NH];
  for (int i = o; i < NH; i += NOUT) hs[i] = h1f[(size_t)b * NH + i];
  __syncthreads();
  const float4* w4 = (const float4*)(Wfc + (size_t)o * NH);
  const float4* h4 = (const float4*)hs;
  float acc = bfc[o];
#pragma unroll 8
  for (int j = 0; j < NH / 4; j++) {
    float4 w = w4[j], h = h4[j];
    acc += w.x * h.x + w.y * h.y + w.z * h.z + w.w * h.w;
  }
  out[(size_t)b * NOUT + o] = acc;
}

extern "C" void kernel_launch(void* const* d_in, const int* in_sizes, int n_in,
                              void* d_out, int out_size, void* d_ws, size_t ws_size,
                              hipStream_t stream) {
  const float* x    = (const float*)d_in[0];
  const float* h0   = (const float*)d_in[1];
  const float* Wih0 = (const float*)d_in[2];
  const float* Whh0 = (const float*)d_in[3];
  const float* bih0 = (const float*)d_in[4];
  const float* bhh0 = (const float*)d_in[5];
  const float* Wih1 = (const float*)d_in[6];
  const float* Whh1 = (const float*)d_in[7];
  const float* bih1 = (const float*)d_in[8];
  const float* bhh1 = (const float*)d_in[9];
  const float* Wfc  = (const float*)d_in[10];
  const float* bfc  = (const float*)d_in[11];
  float* out = (float*)d_out;

  char* ws = (char*)d_ws;
  size_t off = 0;
  u16* pre0 = (u16*)(ws + off); off += (size_t)NB * TSEQ * NH * 2;
  u32* out0 = (u32*)(ws + off); off += (size_t)NB * TSEQ * (NH / 2) * 4;
  u16* pre1 = (u16*)(ws + off); off += (size_t)NB * TSEQ * NH * 2;
  float* h1f = (float*)(ws + off); off += (size_t)NB * NH * 4;
  int* flags = (int*)(ws + off);
  const size_t flagbytes = 256 * 32 * sizeof(int);   // incl. slab-ready lines 200/201
  off += flagbytes;
  u32* gw = (u32*)(ws + off);                        // 2 x 128 KB weight slabs
  // off += 262144;

  hipMemsetAsync(flags, 0, flagbytes, stream);
  hipFuncSetAttribute((const void*)rnn_persist,
                      hipFuncAttributeMaxDynamicSharedMemorySize, SMEM_BYTES);
  rnn_persist<<<160, 512, SMEM_BYTES, stream>>>(
      x, h0, Wih0, Whh0, bih0, bhh0, Wih1, Whh1, bih1, bhh1,
      pre0, out0, pre1, h1f, flags, gw);
  fc_kernel<<<NB, NOUT, 0, stream>>>(h1f, Wfc, bfc, out);
}

// Round 11
// 7414.792 us; speedup vs baseline: 3.3185x; 3.3185x over previous
//
#include <hip/hip_runtime.h>

#define TSEQ 2048
#define NB   20
#define NIN  256
#define NH   512
#define NOUT 128

typedef unsigned int   u32;
typedef unsigned short u16;
typedef _Float16 f16x2 __attribute__((ext_vector_type(2)));

// dynamic LDS layout (uniform 135KB/block also pins 1 block/CU -> all 200 resident)
#define SM_W     0                 // 131072 B: WL uint2[32][512] (pre1)
#define SM_HX    131072            // 2048 B: h exchange, TWO sigma-swizzled f16[512] buffers
#define SM_INP   (131072 + 2048)   // 2048 B: u32 [2][256] input staging (pre roles)
#define SMEM_BYTES (131072 + 2048 + 2048)

// flag-line map (one 128B line each; ALL regions disjoint — r10 hang was
// exchange lines 120-159 colliding with pre1 lines 80-159):
//   0..39   pre0 progress
//   40..79  L0 out0 progress per (b,H)
//   80..159 pre1 progress per (b,sub)
//   200..279 pair-exchange step flags per (L,b,H)
#define XFL_BASE 200
#define FLAG_LINES 320

__device__ __forceinline__ u32 packh2(float a, float b) {
  f16x2 p; p.x = (_Float16)a; p.y = (_Float16)b;
  return __builtin_bit_cast(u32, p);
}

__device__ __forceinline__ float dot2(u32 w, u32 h, float acc) {
  return __builtin_amdgcn_fdot2(__builtin_bit_cast(f16x2, w),
                                __builtin_bit_cast(f16x2, h), acc, false);
}

__device__ __forceinline__ int acq(const int* p) {
  return __hip_atomic_load(p, __ATOMIC_ACQUIRE, __HIP_MEMORY_SCOPE_AGENT);
}
__device__ __forceinline__ void rel(int* p, int v) {
  __hip_atomic_store(p, v, __ATOMIC_RELEASE, __HIP_MEMORY_SCOPE_AGENT);
}
__device__ __forceinline__ void spin_until(const int* p, int need, int& seen) {
  while (seen < need) {
    seen = acq(p);
    if (seen < need) __builtin_amdgcn_s_sleep(1);
  }
}

// ---- IC-coherent (L1/L2-bypass) ops: NO buffer_inv, NO L2 invalidation ----
__device__ __forceinline__ u32 ld_sc01(const u32* p) {
  u32 v;
  asm volatile("global_load_dword %0, %1, off sc0 sc1\n\ts_waitcnt vmcnt(0)"
               : "=v"(v) : "v"(p) : "memory");
  return v;
}
__device__ __forceinline__ void st_sc01(u32* p, u32 v) {
  asm volatile("global_store_dword %0, %1, off sc0 sc1" :: "v"(p), "v"(v) : "memory");
}
// 4x dwordx4 + waitcnt fused in ONE asm block: outputs only live after the
// waitcnt -> consumers can't be hoisted above it (rule-#18-safe).
__device__ __forceinline__ void ld4x_sc01(const u32* p, uint4& a, uint4& b,
                                          uint4& c, uint4& d) {
  asm volatile("global_load_dwordx4 %0, %4, off sc0 sc1\n\t"
               "global_load_dwordx4 %1, %4, off offset:16 sc0 sc1\n\t"
               "global_load_dwordx4 %2, %4, off offset:32 sc0 sc1\n\t"
               "global_load_dwordx4 %3, %4, off offset:48 sc0 sc1\n\t"
               "s_waitcnt vmcnt(0)"
               : "=&v"(a), "=&v"(b), "=&v"(c), "=&v"(d) : "v"(p) : "memory");
}

template<int CTRL>
__device__ __forceinline__ float dpp_add(float x) {
  int v = __builtin_amdgcn_update_dpp(0, __builtin_bit_cast(int, x), CTRL, 0xF, 0xF, true);
  return x + __builtin_bit_cast(float, v);
}
template<int CTRL>
__device__ __forceinline__ u32 dpp_mov_u32(u32 x) {
  return (u32)__builtin_amdgcn_update_dpp(0, (int)x, CTRL, 0xF, 0xF, true);
}

__device__ __forceinline__ float fast_tanh(float x) {
  float xc = fminf(fmaxf(x, -15.f), 15.f);
  float e = __builtin_amdgcn_exp2f(xc * 2.8853900817779268f);  // exp(2x)
  return (e - 1.f) * __builtin_amdgcn_rcpf(e + 1.f);
}

// sigma-swizzle for hx (verified rounds 4-8: SQ_LDS_BANK_CONFLICT = 0)
__device__ __forceinline__ int hx_gran_off(int g, int c) {
  int pg = (g ^ (g >> 2)) & 15;
  return 64 * pg + 16 * (c ^ (g & 3));
}

__device__ __forceinline__ uint4 sel4(bool c, uint4 a, uint4 b) {
  return make_uint4(c ? a.x : b.x, c ? a.y : b.y, c ? a.z : b.z, c ? a.w : b.w);
}

// Persistent fused pipeline. grid = 200 blocks x 512 threads.
//  bid   0..39 : pre0 (b=bid>>1, half=bid&1)  pre0 = x@Wih0^T + bih0 (f16, 8-t tiles)
//  bid  40..79 : L0 pair-half (b=(bid-40)>>1, H=(bid-40)&1): rows [256H,256H+256)
//  bid 80..159 : pre1 (b=(bid-80)>>2, sub&3)  4-way t-chunked gather (8-t tiles)
//  bid160..199 : L1 pair-half (b=(bid-160)>>1, H=(bid-160)&1)
//
// Pair recurrence: ALL weights in VGPR (128 u32/thread); per-step h-half
// exchange via IC-coherent sc0/sc1 stores+loads (no L2-inval acquires).
__global__ __launch_bounds__(512, 2) void rnn_persist(
    const float* __restrict__ x,    const float* __restrict__ h0,
    const float* __restrict__ Wih0, const float* __restrict__ Whh0,
    const float* __restrict__ bih0, const float* __restrict__ bhh0,
    const float* __restrict__ Wih1, const float* __restrict__ Whh1,
    const float* __restrict__ bih1, const float* __restrict__ bhh1,
    u16* __restrict__ pre0, u32* __restrict__ out0,
    u16* __restrict__ pre1, float* __restrict__ h1f,
    int* __restrict__ flags, u32* __restrict__ xb)
{
  extern __shared__ char smem[];
  const int tid = threadIdx.x;
  const int bid = blockIdx.x;

  if (bid < 40) {
    // ---------------- pre0 (verified r5-r7, verbatim) ----------------
    u32* inp = (u32*)(smem + SM_INP);
    const int b = bid >> 1, half = bid & 1, t0 = half * 1024;
    const int n = tid;
    u32 wr[128];
    const float4* W4 = (const float4*)(Wih0 + (size_t)n * NIN);
#pragma unroll
    for (int j = 0; j < 64; j++) {
      float4 w = W4[j];
      wr[2*j] = packh2(w.x, w.y); wr[2*j+1] = packh2(w.z, w.w);
    }
    const float bias = bih0[n];
    const float* xbp = x + ((size_t)b * TSEQ + t0) * NIN;
    u16* op = pre0 + ((size_t)b * TSEQ + t0) * NH;

    float2 r = make_float2(0.f, 0.f);
    if (tid < 128) r = ((const float2*)xbp)[tid];
    int cur = 0;
    for (int t = 0; t < 1024; t++) {
      if (tid < 128) inp[cur * 256 + tid] = packh2(r.x, r.y);
      __syncthreads();
      if (t + 1 < 1024 && tid < 128)
        r = ((const float2*)(xbp + (size_t)(t + 1) * NIN))[tid];
      float a0 = bias, a1 = 0.f;
      const uint4* xp = (const uint4*)(inp + cur * 256);
#pragma unroll
      for (int j = 0; j < 32; j++) {
        uint4 hv = xp[j];
        a0 = dot2(wr[4*j+0], hv.x, a0); a1 = dot2(wr[4*j+1], hv.y, a1);
        a0 = dot2(wr[4*j+2], hv.z, a0); a1 = dot2(wr[4*j+3], hv.w, a1);
      }
      op[((size_t)(t >> 3) * NH + n) * 8 + (t & 7)] =
          __builtin_bit_cast(u16, (_Float16)(a0 + a1));
      cur ^= 1;
      if (((t + 1) & 7) == 0) {
        __syncthreads();
        if (tid == 0) rel(flags + bid * 32, t + 1);
      }
    }
    return;
  }

  if (bid >= 80 && bid < 160) {
    // ---------------- pre1 (verified structure; waits BOTH L0 halves) ----------------
    uint2* WL  = (uint2*)(smem + SM_W);
    u32*   inp = (u32*)(smem + SM_INP);
    const int b = (bid - 80) >> 2, sub = (bid - 80) & 3;
    const int n = tid;
    u32 wr[192];
    const float4* W4 = (const float4*)(Wih1 + (size_t)n * NH);
#pragma unroll
    for (int j = 0; j < 96; j++) {
      float4 w = W4[j];
      wr[2*j] = packh2(w.x, w.y); wr[2*j+1] = packh2(w.z, w.w);
    }
#pragma unroll
    for (int j2 = 0; j2 < 32; j2++) {
      float4 w = W4[96 + j2];
      WL[j2 * NH + n] = make_uint2(packh2(w.x, w.y), packh2(w.z, w.w));
    }
    const float bias = bih1[n];
    __syncthreads();

    const u32* ip = out0 + (size_t)b * TSEQ * 256;
    u16* op = pre1 + (size_t)b * TSEQ * NH;
    const int* fH0 = flags + (40 + b * 2 + 0) * 32;
    const int* fH1 = flags + (40 + b * 2 + 1) * 32;
    int* flagMy = flags + (80 + b * 4 + sub) * 32;
    int sH0 = 0, sH1 = 0, cur = 0;
#pragma unroll 1
    for (int c = sub; c < TSEQ / 8; c += 4) {
      const int tbase = c * 8;
      spin_until(fH0, tbase + 8, sH0);
      spin_until(fH1, tbase + 8, sH1);
      u32 rin = (tid < 256) ? ip[(size_t)tbase * 256 + tid] : 0;
#pragma unroll 1
      for (int qq = 0; qq < 8; qq++) {
        const int t = tbase + qq;
        if (tid < 256) inp[cur * 256 + tid] = rin;
        __syncthreads();
        if (qq + 1 < 8 && tid < 256) rin = ip[(size_t)(t + 1) * 256 + tid];
        float a0 = bias, a1 = 0.f;
        const uint4* hp4 = (const uint4*)(inp + cur * 256);
#pragma unroll
        for (int j = 0; j < 48; j++) {
          uint4 hv = hp4[j];
          a0 = dot2(wr[4*j+0], hv.x, a0); a1 = dot2(wr[4*j+1], hv.y, a1);
          a0 = dot2(wr[4*j+2], hv.z, a0); a1 = dot2(wr[4*j+3], hv.w, a1);
        }
#pragma unroll
        for (int jj = 0; jj < 16; jj++) {
          uint4 hv = hp4[48 + jj];
          uint2 w0 = WL[(2*jj)   * NH + n];
          uint2 w1 = WL[(2*jj+1) * NH + n];
          a0 = dot2(w0.x, hv.x, a0); a1 = dot2(w0.y, hv.y, a1);
          a0 = dot2(w1.x, hv.z, a0); a1 = dot2(w1.y, hv.w, a1);
        }
        op[((size_t)(t >> 3) * NH + n) * 8 + (t & 7)] =
            __builtin_bit_cast(u16, (_Float16)(a0 + a1));
        cur ^= 1;
      }
      __syncthreads();
      if (tid == 0) rel(flagMy, tbase + 8);
    }
    return;
  }

  // ---------------- L0 / L1 paired recurrence ----------------
  const bool isL0 = (bid < 160);
  const int idx = isL0 ? (bid - 40) : (bid - 160);
  const int b = idx >> 1, H = idx & 1, L = isL0 ? 0 : 1;
  const float* Wg = isL0 ? Whh0 : Whh1;
  const float* bp = isL0 ? bhh0 : bhh1;

  char* hxc = smem + SM_HX;             // 2x sigma-swizzled f16[512]

  const int lam = tid & 15;             // k-granule: k in [32*lam, 32*lam+32)
  const int ns  = tid >> 4;             // row group: rows 256H + 8*ns .. +8
  const int rbase0 = 256 * H + 8 * ns;
  const int n = rbase0 + (lam & 7);     // my output row (lanes lam, lam+8 dup)
  const bool inhalf = H ? (lam >= 8) : (lam < 8);  // my k-granule in my row-half?

  // ALL weights in registers: wj[j] = W row (rbase0+j), cols [32lam, 32lam+32)
  u32 wj[8][16];
#pragma unroll
  for (int j = 0; j < 8; j++) {
    const float4* Wr = (const float4*)(Wg + (size_t)(rbase0 + j) * NH + 32 * lam);
#pragma unroll
    for (int k4 = 0; k4 < 8; k4++) {
      float4 w = Wr[k4];
      wj[j][2*k4] = packh2(w.x, w.y); wj[j][2*k4+1] = packh2(w.z, w.w);
    }
  }
  const float bias = bp[n];

  // hx addresses (loop-invariant)
  int hadr[4];
#pragma unroll
  for (int c = 0; c < 4; c++) hadr[c] = hx_gran_off(lam, c);
  const int wgi = (n >> 5) & 15, wci = (n >> 3) & 3;
  const int waddr = hx_gran_off(wgi, wci) + (n & 7) * 2;   // my h[n] LDS slot
  const bool b0 = (tid & 1), b1 = (tid & 2), b2 = (tid & 4);

  // init hx buffer 0 with FULL h0 (t=0 reads LDS for all lanes)
  {
    const int wg0 = (tid >> 5) & 15, wc0 = (tid >> 3) & 3;
    *(u16*)(hxc + hx_gran_off(wg0, wc0) + (tid & 7) * 2) =
        __builtin_bit_cast(u16, (_Float16)h0[(L * NB + b) * NH + tid]);
  }
  __syncthreads();

  // exchange buffers / flags (lines XFL_BASE.. — disjoint from all others)
  u32* xb_my = xb + ((size_t)((L * 20 + b) * 2 + H) * 2) * 128;
  const u32* xb_pt = xb + ((size_t)((L * 20 + b) * 2 + (1 - H)) * 2) * 128;
  u32* xfl_my = (u32*)(flags + (XFL_BASE + (L * 20 + b) * 2 + H) * 32);
  const u32* xfl_pt = (const u32*)(flags + (XFL_BASE + (L * 20 + b) * 2 + (1 - H)) * 32);
  const int xoff = (16 * lam) & 127;    // my k-granules inside partner half (u32 idx)

  const uint4* pin4 = (const uint4*)((isL0 ? pre0 : pre1) + (size_t)b * TSEQ * NH);
  u32* o0p = out0 + (size_t)b * TSEQ * 256;
  int* flagOutH = flags + (40 + b * 2 + H) * 32;
  const int* f0 = flags + (b * 2 + 0) * 32;       // pre0 halves (L0)
  const int* f1 = flags + (b * 2 + 1) * 32;
  const int* fpA = flags + (80 + b * 4 + 0) * 32; // pre1 subs (L1)
  const int* fpB = flags + (80 + b * 4 + 1) * 32;
  const int* fpC = flags + (80 + b * 4 + 2) * 32;
  const int* fpD = flags + (80 + b * 4 + 3) * 32;
  int s0 = 0, s1 = 0, sA = 0, sB = 0, sC = 0, sD = 0;

  // prologue: chunk 0 and 1 pre-activations
  if (isL0) { spin_until(f0, 8, s0); }  else { spin_until(fpA, 8, sA); }
  uint4 pcur4 = pin4[n];
  if (isL0) { spin_until(f0, 16, s0); } else { spin_until(fpB, 16, sB); }
  uint4 pnext4 = pin4[512 + n];

  const bool pk_act = inhalf && !(lam & 1);       // pack/store lane for rows (n, n+1)
  const int gidx = n >> 1;                        // out0 u32 index
  const int lidx = gidx & 127;                    // xbuf u32 index

  float hlast = 0.f;
#pragma unroll 1
  for (int c = 0; c < TSEQ / 8; c++) {
#pragma unroll 1
    for (int q = 0; q < 8; q++) {
      const int t = c * 8 + q;
      const int rbase = (t & 1) << 10;

      // partner half of h(t-1): poll flag >= t, then direct IC loads (wait fused)
      uint4 g0 = make_uint4(0,0,0,0), g1 = g0, g2 = g0, g3 = g0;
      if (t != 0) {
        while (ld_sc01(xfl_pt) < (u32)t) __builtin_amdgcn_s_sleep(1);
        ld4x_sc01(xb_pt + (size_t)((t - 1) & 1) * 128 + xoff, g0, g1, g2, g3);
      }
      // own half from LDS (both halves at t==0: full h0 was staged)
      const uint4 l0 = *(const uint4*)(hxc + rbase + hadr[0]);
      const uint4 l1 = *(const uint4*)(hxc + rbase + hadr[1]);
      const uint4 l2 = *(const uint4*)(hxc + rbase + hadr[2]);
      const uint4 l3 = *(const uint4*)(hxc + rbase + hadr[3]);
      const bool useL = inhalf || (t == 0);
      const uint4 hv0 = sel4(useL, l0, g0);
      const uint4 hv1 = sel4(useL, l1, g1);
      const uint4 hv2 = sel4(useL, l2, g2);
      const uint4 hv3 = sel4(useL, l3, g3);

      // 8 rows x 16 dot2
      float a0=0.f,a1=0.f,a2=0.f,a3=0.f,a4=0.f,a5=0.f,a6=0.f,a7=0.f;
#define ROWD(acc, WR)                                               \
      acc = dot2(WR[0],  hv0.x, acc); acc = dot2(WR[1],  hv0.y, acc); \
      acc = dot2(WR[2],  hv0.z, acc); acc = dot2(WR[3],  hv0.w, acc); \
      acc = dot2(WR[4],  hv1.x, acc); acc = dot2(WR[5],  hv1.y, acc); \
      acc = dot2(WR[6],  hv1.z, acc); acc = dot2(WR[7],  hv1.w, acc); \
      acc = dot2(WR[8],  hv2.x, acc); acc = dot2(WR[9],  hv2.y, acc); \
      acc = dot2(WR[10], hv2.z, acc); acc = dot2(WR[11], hv2.w, acc); \
      acc = dot2(WR[12], hv3.x, acc); acc = dot2(WR[13], hv3.y, acc); \
      acc = dot2(WR[14], hv3.z, acc); acc = dot2(WR[15], hv3.w, acc)
      ROWD(a0, wj[0]); ROWD(a1, wj[1]); ROWD(a2, wj[2]); ROWD(a3, wj[3]);
      ROWD(a4, wj[4]); ROWD(a5, wj[5]); ROWD(a6, wj[6]); ROWD(a7, wj[7]);
#undef ROWD

      // tree: r7-verified pattern, one level shorter (8 rows over 16 lanes)
      float t0 = dpp_add<0xB1>(a0), t1 = dpp_add<0xB1>(a1);
      float t2 = dpp_add<0xB1>(a2), t3 = dpp_add<0xB1>(a3);
      float u0 = b0 ? t1 : t0, u1 = b0 ? t3 : t2;
      u0 = dpp_add<0x4E>(u0); u1 = dpp_add<0x4E>(u1);
      float G0 = b1 ? u1 : u0;
      t0 = dpp_add<0xB1>(a4); t1 = dpp_add<0xB1>(a5);
      t2 = dpp_add<0xB1>(a6); t3 = dpp_add<0xB1>(a7);
      u0 = b0 ? t1 : t0; u1 = b0 ? t3 : t2;
      u0 = dpp_add<0x4E>(u0); u1 = dpp_add<0x4E>(u1);
      float G1 = b1 ? u1 : u0;
      G0 = dpp_add<0x124>(G0); G1 = dpp_add<0x124>(G1);
      float r = b2 ? G1 : G0;
      r = dpp_add<0x128>(r);
      const float red = r;

      // pre-activation q from pcur4
      const u32 wlo  = (q & 4) ? pcur4.z : pcur4.x;
      const u32 whi  = (q & 4) ? pcur4.w : pcur4.y;
      const u32 wsel = (q & 2) ? whi : wlo;
      const u16 pq   = (u16)((q & 1) ? (wsel >> 16) : (wsel & 0xffffu));

      const float h = fast_tanh(red + bias + (float)__builtin_bit_cast(_Float16, pq));
      hlast = h;
      const u16 h16 = __builtin_bit_cast(u16, (_Float16)h);
      const int wbase = rbase ^ 1024;
      if (inhalf) *(u16*)(hxc + wbase + waddr) = h16;

      // pack row-pair and export: exchange (sc0/sc1) + out0 (L0, normal)
      {
        u32 v = (u32)h16;
        u32 nb = dpp_mov_u32<0xB1>(v);
        u32 pk = v | (nb << 16);
        if (pk_act) {
          st_sc01(xb_my + (size_t)(t & 1) * 128 + lidx, pk);
          if (isL0) o0p[(size_t)t * 256 + gidx] = pk;
        }
      }

      // drain stores + LDS, block-wide; then publish my step flag
      asm volatile("s_waitcnt vmcnt(0) lgkmcnt(0)" ::: "memory");
      __builtin_amdgcn_s_barrier();
      if (tid == 0) st_sc01(xfl_my, (u32)(t + 1));
    }

    if (isL0 && tid == 0) rel(flagOutH, c * 8 + 8);

    // rotate chunk buffers, prefetch chunk c+2
    pcur4 = pnext4;
    if (c < TSEQ / 8 - 2) {
      const int c2 = c + 2;
      const int need = 8 * (c2 + 1);
      if (isL0) {
        if (c2 < 128) { spin_until(f0, need, s0); }
        else          { spin_until(f1, need - 1024, s1); }
      } else {
        const int w = c2 & 3;
        if      (w == 0) { spin_until(fpA, need, sA); }
        else if (w == 1) { spin_until(fpB, need, sB); }
        else if (w == 2) { spin_until(fpC, need, sC); }
        else             { spin_until(fpD, need, sD); }
      }
      pnext4 = pin4[(size_t)c2 * 512 + n];
    }
  }

  if (!isL0 && inhalf) h1f[(size_t)b * NH + n] = hlast;
}

__global__ void fc_kernel(const float* __restrict__ h1f, const float* __restrict__ Wfc,
                          const float* __restrict__ bfc, float* __restrict__ out) {
  const int b = blockIdx.x, o = threadIdx.x;  // 20 blocks x 128 threads
  __shared__ float hs[NH];
  for (int i = o; i < NH; i += NOUT) hs[i] = h1f[(size_t)b * NH + i];
  __syncthreads();
  const float4* w4 = (const float4*)(Wfc + (size_t)o * NH);
  const float4* h4 = (const float4*)hs;
  float acc = bfc[o];
#pragma unroll 8
  for (int j = 0; j < NH / 4; j++) {
    float4 w = w4[j], h = h4[j];
    acc += w.x * h.x + w.y * h.y + w.z * h.z + w.w * h.w;
  }
  out[(size_t)b * NOUT + o] = acc;
}

extern "C" void kernel_launch(void* const* d_in, const int* in_sizes, int n_in,
                              void* d_out, int out_size, void* d_ws, size_t ws_size,
                              hipStream_t stream) {
  const float* x    = (const float*)d_in[0];
  const float* h0   = (const float*)d_in[1];
  const float* Wih0 = (const float*)d_in[2];
  const float* Whh0 = (const float*)d_in[3];
  const float* bih0 = (const float*)d_in[4];
  const float* bhh0 = (const float*)d_in[5];
  const float* Wih1 = (const float*)d_in[6];
  const float* Whh1 = (const float*)d_in[7];
  const float* bih1 = (const float*)d_in[8];
  const float* bhh1 = (const float*)d_in[9];
  const float* Wfc  = (const float*)d_in[10];
  const float* bfc  = (const float*)d_in[11];
  float* out = (float*)d_out;

  char* ws = (char*)d_ws;
  size_t off = 0;
  u16* pre0 = (u16*)(ws + off); off += (size_t)NB * TSEQ * NH * 2;
  u32* out0 = (u32*)(ws + off); off += (size_t)NB * TSEQ * (NH / 2) * 4;
  u16* pre1 = (u16*)(ws + off); off += (size_t)NB * TSEQ * NH * 2;
  float* h1f = (float*)(ws + off); off += (size_t)NB * NH * 4;
  int* flags = (int*)(ws + off);
  const size_t flagbytes = FLAG_LINES * 32 * sizeof(int);
  off += flagbytes;
  u32* xb = (u32*)(ws + off);                       // 80 KB exchange buffers
  // off += 80 * 2 * 128 * 4;

  (void)hipMemsetAsync(flags, 0, flagbytes, stream);
  (void)hipFuncSetAttribute((const void*)rnn_persist,
                            hipFuncAttributeMaxDynamicSharedMemorySize, SMEM_BYTES);
  rnn_persist<<<200, 512, SMEM_BYTES, stream>>>(
      x, h0, Wih0, Whh0, bih0, bhh0, Wih1, Whh1, bih1, bhh1,
      pre0, out0, pre1, h1f, flags, xb);
  fc_kernel<<<NB, NOUT, 0, stream>>>(h1f, Wfc, bfc, out);
}

// Round 13
// 6594.885 us; speedup vs baseline: 3.7311x; 1.1243x over previous
//
#include <hip/hip_runtime.h>

#define TSEQ 2048
#define NB   20
#define NIN  256
#define NH   512
#define NOUT 128

typedef unsigned int   u32;
typedef unsigned short u16;
typedef _Float16 f16x2 __attribute__((ext_vector_type(2)));

// dynamic LDS layout
#define SM_W     0                 // 131072 B: WL uint2[32][512] (pre1 only)
#define SM_HX    131072            // 2048 B: h exchange, TWO sigma-swizzled f16[512] buffers
#define SM_INP   (131072 + 2048)   // 2048 B: u32 [2][256] input staging (pre roles)
#define SMEM_BYTES (131072 + 2048 + 2048)

// flag lines (128B each, all disjoint): 0-39 pre0 | 40-59 out0 per b |
// 60-139 pre1 per (b,sub) | 200-201 slab-ready per layer
#define FLAG_LINES 256

__device__ __forceinline__ u32 packh2(float a, float b) {
  f16x2 p; p.x = (_Float16)a; p.y = (_Float16)b;
  return __builtin_bit_cast(u32, p);
}

__device__ __forceinline__ float dot2(u32 w, u32 h, float acc) {
  return __builtin_amdgcn_fdot2(__builtin_bit_cast(f16x2, w),
                                __builtin_bit_cast(f16x2, h), acc, false);
}

// ---- IC-coherent (L1/L2-bypass) ops: NO buffer_inv -> L2 stays warm ----
// gfx950 inline-asm rule (r9/r12 lesson): SCALAR inputs only; aggregates
// (uint4) are legal only as OUTPUTS.
__device__ __forceinline__ u32 ld_sc01(const u32* p) {
  u32 v;
  asm volatile("global_load_dword %0, %1, off sc0 sc1\n\ts_waitcnt vmcnt(0)"
               : "=v"(v) : "v"(p) : "memory");
  return v;
}
__device__ __forceinline__ void st_sc01(u32* p, u32 v) {
  asm volatile("global_store_dword %0, %1, off sc0 sc1" :: "v"(p), "v"(v) : "memory");
}
__device__ __forceinline__ void st_sc01_u16(u16* p, u32 v) {
  asm volatile("global_store_short %0, %1, off sc0 sc1" :: "v"(p), "v"(v) : "memory");
}
__device__ __forceinline__ uint4 ld1x4_sc01(const void* p) {
  uint4 v;
  asm volatile("global_load_dwordx4 %0, %1, off sc0 sc1\n\ts_waitcnt vmcnt(0)"
               : "=v"(v) : "v"(p) : "memory");
  return v;
}
// poll with cached last-seen value (monotone flags): most polls are free
__device__ __forceinline__ void spin_sc01(const u32* p, u32 need, u32& seen) {
  while (seen < need) {
    seen = ld_sc01(p);
    if (seen < need) __builtin_amdgcn_s_sleep(1);
  }
}
// acquire/release (agent scope): INIT-ONLY — acq emits buffer_inv (L2 inval),
// rel emits buffer_wbl2 (L2 writeback). Never in steady state (r8 lesson).
__device__ __forceinline__ int acq(const int* p) {
  return __hip_atomic_load(p, __ATOMIC_ACQUIRE, __HIP_MEMORY_SCOPE_AGENT);
}
__device__ __forceinline__ void rel(int* p, int v) {
  __hip_atomic_store(p, v, __ATOMIC_RELEASE, __HIP_MEMORY_SCOPE_AGENT);
}

// LDS-only barrier: orders LDS without draining vmcnt (sc01 stores stay in flight)
__device__ __forceinline__ void lds_barrier() {
  asm volatile("s_waitcnt lgkmcnt(0)\n\ts_barrier" ::: "memory");
}
#define VM_DRAIN() asm volatile("s_waitcnt vmcnt(0)" ::: "memory")

template<int CTRL>
__device__ __forceinline__ float dpp_add(float x) {
  int v = __builtin_amdgcn_update_dpp(0, __builtin_bit_cast(int, x), CTRL, 0xF, 0xF, true);
  return x + __builtin_bit_cast(float, v);
}
template<int CTRL>
__device__ __forceinline__ u32 dpp_mov_u32(u32 x) {
  return (u32)__builtin_amdgcn_update_dpp(0, (int)x, CTRL, 0xF, 0xF, true);
}

__device__ __forceinline__ float fast_tanh(float x) {
  float xc = fminf(fmaxf(x, -15.f), 15.f);
  float e = __builtin_amdgcn_exp2f(xc * 2.8853900817779268f);  // exp(2x)
  return (e - 1.f) * __builtin_amdgcn_rcpf(e + 1.f);
}

// sigma-swizzle for hx (verified rounds 4-8: SQ_LDS_BANK_CONFLICT = 0)
__device__ __forceinline__ int hx_gran_off(int g, int c) {
  int pg = (g ^ (g >> 2)) & 15;
  return 64 * pg + 16 * (c ^ (g & 3));
}

// Persistent fused pipeline. grid = 160 blocks x 512 threads (r7/r8 roles).
//  bid   0..39 : pre0 (b=bid>>1, half=bid&1)
//  bid  40..59 : L0 recurrence (b=bid-40)
//  bid 60..139 : pre1 (b=(bid-60)>>2, sub=(bid-60)&3)
//  bid140..159 : L1 recurrence (b=bid-140)
//
// r13 = r8's global-slab design, acquire-free steady state:
//  - overflow weight rows in a per-layer 128KB GLOBAL slab, L2-cached (warm:
//    nothing invalidates L2 in steady state) -> LDS pipe freed (r7's wall)
//  - slab handshake: plain stores + ONE rel/acq at init (r8-verified path)
//  - all steady-state polls are sc0/sc1 raw loads; cross-block data sc0/sc1.
__global__ __launch_bounds__(512, 2) void rnn_persist(
    const float* __restrict__ x,    const float* __restrict__ h0,
    const float* __restrict__ Wih0, const float* __restrict__ Whh0,
    const float* __restrict__ bih0, const float* __restrict__ bhh0,
    const float* __restrict__ Wih1, const float* __restrict__ Whh1,
    const float* __restrict__ bih1, const float* __restrict__ bhh1,
    u16* __restrict__ pre0, u32* __restrict__ out0,
    u16* __restrict__ pre1, float* __restrict__ h1f,
    int* __restrict__ flags, u32* __restrict__ gw)
{
  extern __shared__ char smem[];
  const int tid = threadIdx.x;
  const int bid = blockIdx.x;
  u32* uflags = (u32*)flags;

  if (bid < 40) {
    // ---------------- pre0: x @ Wih0^T + bih0 (tiled, sc01 stores) ----------------
    u32* inp = (u32*)(smem + SM_INP);
    const int b = bid >> 1, half = bid & 1, t0 = half * 1024;
    const int n = tid;
    u32 wr[128];
    const float4* W4 = (const float4*)(Wih0 + (size_t)n * NIN);
#pragma unroll
    for (int j = 0; j < 64; j++) {
      float4 w = W4[j];
      wr[2*j] = packh2(w.x, w.y); wr[2*j+1] = packh2(w.z, w.w);
    }
    const float bias = bih0[n];
    const float* xbp = x + ((size_t)b * TSEQ + t0) * NIN;
    u16* op = pre0 + ((size_t)b * TSEQ + t0) * NH;
    u32* myflag = uflags + bid * 32;

    float2 r = make_float2(0.f, 0.f);
    if (tid < 128) r = ((const float2*)xbp)[tid];
    int cur = 0;
    for (int t = 0; t < 1024; t++) {
      if (tid < 128) inp[cur * 256 + tid] = packh2(r.x, r.y);
      __syncthreads();
      if (t + 1 < 1024 && tid < 128)
        r = ((const float2*)(xbp + (size_t)(t + 1) * NIN))[tid];
      float a0 = bias, a1 = 0.f;
      const uint4* xp = (const uint4*)(inp + cur * 256);
#pragma unroll
      for (int j = 0; j < 32; j++) {
        uint4 hv = xp[j];
        a0 = dot2(wr[4*j+0], hv.x, a0); a1 = dot2(wr[4*j+1], hv.y, a1);
        a0 = dot2(wr[4*j+2], hv.z, a0); a1 = dot2(wr[4*j+3], hv.w, a1);
      }
      const float v = a0 + a1;
      st_sc01_u16(&op[((size_t)(t >> 3) * NH + n) * 8 + (t & 7)],
                  (u32)__builtin_bit_cast(u16, (_Float16)v));
      cur ^= 1;
      if (((t + 1) & 7) == 0) {
        VM_DRAIN();                 // asm stores are invisible to compiler waitcnt
        __syncthreads();
        if (tid == 0) st_sc01(myflag, (u32)(t + 1));
      }
    }
    return;
  }

  if (bid >= 60 && bid < 140) {
    // ---------------- pre1: out0 @ Wih1^T + bih1, 4-way t-chunk split ----------------
    uint2* WL  = (uint2*)(smem + SM_W);
    u32*   inp = (u32*)(smem + SM_INP);
    const int b = (bid - 60) >> 2, sub = (bid - 60) & 3;
    const int n = tid;
    u32 wr[192];
    const float4* W4 = (const float4*)(Wih1 + (size_t)n * NH);
#pragma unroll
    for (int j = 0; j < 96; j++) {
      float4 w = W4[j];
      wr[2*j] = packh2(w.x, w.y); wr[2*j+1] = packh2(w.z, w.w);
    }
#pragma unroll
    for (int j2 = 0; j2 < 32; j2++) {
      float4 w = W4[96 + j2];
      WL[j2 * NH + n] = make_uint2(packh2(w.x, w.y), packh2(w.z, w.w));
    }
    const float bias = bih1[n];
    __syncthreads();

    const u32* ip = out0 + (size_t)b * TSEQ * 256;
    u16* op = pre1 + (size_t)b * TSEQ * NH;
    const u32* flagOut0 = uflags + (40 + b) * 32;
    u32* flagMy = uflags + (60 + b * 4 + sub) * 32;
    u32 seen = 0; int cur = 0;
#pragma unroll 1
    for (int c = sub; c < TSEQ / 8; c += 4) {
      const int tbase = c * 8;
      spin_sc01(flagOut0, (u32)(tbase + 8), seen);
      u32 rin = (tid < 256) ? ld_sc01(&ip[(size_t)tbase * 256 + tid]) : 0;
#pragma unroll 1
      for (int qq = 0; qq < 8; qq++) {
        const int t = tbase + qq;
        if (tid < 256) inp[cur * 256 + tid] = rin;
        __syncthreads();
        if (qq + 1 < 8 && tid < 256)
          rin = ld_sc01(&ip[(size_t)(t + 1) * 256 + tid]);
        float a0 = bias, a1 = 0.f;
        const uint4* hp4 = (const uint4*)(inp + cur * 256);
#pragma unroll
        for (int j = 0; j < 48; j++) {
          uint4 hv = hp4[j];
          a0 = dot2(wr[4*j+0], hv.x, a0); a1 = dot2(wr[4*j+1], hv.y, a1);
          a0 = dot2(wr[4*j+2], hv.z, a0); a1 = dot2(wr[4*j+3], hv.w, a1);
        }
#pragma unroll
        for (int jj = 0; jj < 16; jj++) {
          uint4 hv = hp4[48 + jj];
          uint2 w0 = WL[(2*jj)   * NH + n];
          uint2 w1 = WL[(2*jj+1) * NH + n];
          a0 = dot2(w0.x, hv.x, a0); a0 = dot2(w0.y, hv.y, a0);
          a1 = dot2(w1.x, hv.z, a1); a1 = dot2(w1.y, hv.w, a1);
        }
        const float v = a0 + a1;
        st_sc01_u16(&op[((size_t)(t >> 3) * NH + n) * 8 + (t & 7)],
                    (u32)__builtin_bit_cast(u16, (_Float16)v));
        cur ^= 1;
      }
      VM_DRAIN();
      __syncthreads();
      if (tid == 0) st_sc01(flagMy, (u32)(tbase + 8));
    }
    return;
  }

  // ---------------- L0 / L1 recurrence: grouped DPP tree + L2-warm slab ----------------
  const bool isL0 = (bid < 60);
  const int b = isL0 ? (bid - 40) : (bid - 140);
  const float* Wg = isL0 ? Whh0 : Whh1;
  const float* bp = isL0 ? bhh0 : bhh1;

  char* hxc = smem + SM_HX;             // 2x sigma-swizzled f16[512]
  uint4* GW4 = (uint4*)(gw + (isL0 ? 0 : 1) * 32768);   // per-layer 128KB slab
  int* slabF = flags + (200 + (isL0 ? 0 : 1)) * 32;

  const int lam = tid & 15;             // k-granule: k in [32*lam, 32*lam+32)
  const int ns  = tid >> 4;             // n-slice: rows 16*ns .. 16*ns+15

  // Register rows: group g holds matrix rows 16*ns + {4g,4g+1,4g+2} in wj[3g+m].
  u32 wj[12][16];
#pragma unroll
  for (int g = 0; g < 4; g++) {
#pragma unroll
    for (int m = 0; m < 3; m++) {
      const float4* Wr = (const float4*)(Wg + (size_t)(16 * ns + 4 * g + m) * NH + 32 * lam);
#pragma unroll
      for (int k4 = 0; k4 < 8; k4++) {
        float4 w = Wr[k4];
        wj[3*g+m][2*k4] = packh2(w.x, w.y); wj[3*g+m][2*k4+1] = packh2(w.z, w.w);
      }
    }
  }
  // Overflow rows (16*ns + 4g+3): b==0 packs them once into the slab.
  // PLAIN stores + release below (init-only handshake, r8-verified).
  if (b == 0) {
#pragma unroll
    for (int g = 0; g < 4; g++) {
      const float4* Wr = (const float4*)(Wg + (size_t)(16 * ns + 4 * g + 3) * NH + 32 * lam);
#pragma unroll
      for (int q = 0; q < 4; q++) {
        float4 wA = Wr[2*q], wB = Wr[2*q+1];
        GW4[(4 * g + q) * 512 + tid] =
            make_uint4(packh2(wA.x, wA.y), packh2(wA.z, wA.w),
                       packh2(wB.x, wB.y), packh2(wB.z, wB.w));
      }
    }
  }
  const float bias = bp[tid];           // final owner n == tid

  int hadr[4];
#pragma unroll
  for (int c = 0; c < 4; c++) hadr[c] = hx_gran_off(lam, c);
  const int wg = (tid >> 5) & 15, wc = (tid >> 3) & 3;
  const int waddr = hx_gran_off(wg, wc) + (tid & 7) * 2;  // my h[tid] slot
  const bool b0 = (tid & 1), b1 = (tid & 2), b2 = (tid & 4), b3 = (tid & 8);

  // init hx buffer 0 with h0
  *(u16*)(hxc + waddr) =
      __builtin_bit_cast(u16, (_Float16)h0[((isL0 ? 0 : 1) * NB + b) * NH + tid]);
  __syncthreads();   // drains slab stores (plain, compiler-tracked) + hx write
  if (b == 0 && tid == 0) rel(slabF, 1);   // wbl2: slab -> IC; flag at coherent point
  // INIT-ONLY acquire spin: last acq invalidates my L2 -> fresh slab from IC;
  // afterwards nothing invalidates L2 again (all steady-state polls are sc01).
  { int sv = 0; while (sv < 1) { sv = acq(slabF); if (sv < 1) __builtin_amdgcn_s_sleep(1); } }

  const uint4* pin4 =
      (const uint4*)((isL0 ? pre0 : pre1) + (size_t)b * TSEQ * NH);
  u32* o0p = out0 + (size_t)b * TSEQ * 256;
  u32* flagOut0 = uflags + (40 + b) * 32;
  const u32* f0 = uflags + (b * 2 + 0) * 32;       // pre0 halves (L0)
  const u32* f1 = uflags + (b * 2 + 1) * 32;
  const u32* fpA = uflags + (60 + b * 4 + 0) * 32; // pre1 subs (L1)
  const u32* fpB = uflags + (60 + b * 4 + 1) * 32;
  const u32* fpC = uflags + (60 + b * 4 + 2) * 32;
  const u32* fpD = uflags + (60 + b * 4 + 3) * 32;
  u32 s0 = 0, s1 = 0, sA = 0, sB = 0, sC = 0, sD = 0;

  // prologue: fetch chunk 0 into pcur4, chunk 1 into pnext4 (IC-direct)
  if (isL0) { spin_sc01(f0, 8u, s0); }  else { spin_sc01(fpA, 8u, sA); }
  uint4 pcur4 = ld1x4_sc01(&pin4[tid]);
  if (isL0) { spin_sc01(f0, 16u, s0); } else { spin_sc01(fpB, 16u, sB); }
  uint4 pnext4 = ld1x4_sc01(&pin4[512 + tid]);

#define ROW16(acc, WR)                                              \
    acc = dot2(WR[0],  hv0.x, acc); acc = dot2(WR[1],  hv0.y, acc); \
    acc = dot2(WR[2],  hv0.z, acc); acc = dot2(WR[3],  hv0.w, acc); \
    acc = dot2(WR[4],  hv1.x, acc); acc = dot2(WR[5],  hv1.y, acc); \
    acc = dot2(WR[6],  hv1.z, acc); acc = dot2(WR[7],  hv1.w, acc); \
    acc = dot2(WR[8],  hv2.x, acc); acc = dot2(WR[9],  hv2.y, acc); \
    acc = dot2(WR[10], hv2.z, acc); acc = dot2(WR[11], hv2.w, acc); \
    acc = dot2(WR[12], hv3.x, acc); acc = dot2(WR[13], hv3.y, acc); \
    acc = dot2(WR[14], hv3.z, acc); acc = dot2(WR[15], hv3.w, acc)

  // group gi: rows 4gi..4gi+2 from regs, row 4gi+3 from the L2-warm slab
#define GROUP(gi, OUT)                                               \
  {                                                                  \
    const uint4 wvA = GW4[(4*gi + 0) * 512 + tid];                   \
    const uint4 wvB = GW4[(4*gi + 1) * 512 + tid];                   \
    const uint4 wvC = GW4[(4*gi + 2) * 512 + tid];                   \
    const uint4 wvD = GW4[(4*gi + 3) * 512 + tid];                   \
    float a0 = 0.f, a1 = 0.f, a2 = 0.f, a3 = 0.f;                    \
    ROW16(a0, wj[3*gi+0]);                                           \
    ROW16(a1, wj[3*gi+1]);                                           \
    ROW16(a2, wj[3*gi+2]);                                           \
    a3 = dot2(wvA.x, hv0.x, a3); a3 = dot2(wvA.y, hv0.y, a3);        \
    a3 = dot2(wvA.z, hv0.z, a3); a3 = dot2(wvA.w, hv0.w, a3);        \
    a3 = dot2(wvB.x, hv1.x, a3); a3 = dot2(wvB.y, hv1.y, a3);        \
    a3 = dot2(wvB.z, hv1.z, a3); a3 = dot2(wvB.w, hv1.w, a3);        \
    a3 = dot2(wvC.x, hv2.x, a3); a3 = dot2(wvC.y, hv2.y, a3);        \
    a3 = dot2(wvC.z, hv2.z, a3); a3 = dot2(wvC.w, hv2.w, a3);        \
    a3 = dot2(wvD.x, hv3.x, a3); a3 = dot2(wvD.y, hv3.y, a3);        \
    a3 = dot2(wvD.z, hv3.z, a3); a3 = dot2(wvD.w, hv3.w, a3);        \
    float t0 = dpp_add<0xB1>(a0), t1 = dpp_add<0xB1>(a1);            \
    float t2 = dpp_add<0xB1>(a2), t3 = dpp_add<0xB1>(a3);            \
    float u0 = b0 ? t1 : t0, u1 = b0 ? t3 : t2;                      \
    u0 = dpp_add<0x4E>(u0); u1 = dpp_add<0x4E>(u1);                  \
    OUT = b1 ? u1 : u0;                                              \
  }

  float hlast = 0.f;
#pragma unroll 1
  for (int c = 0; c < TSEQ / 8; c++) {
#pragma unroll 1
    for (int q = 0; q < 8; q++) {
      const int t = c * 8 + q;
      const int rbase = (t & 1) << 10;   // read buffer
      const int wbase = rbase ^ 1024;    // write buffer

      const uint4 hv0 = *(const uint4*)(hxc + rbase + hadr[0]);
      const uint4 hv1 = *(const uint4*)(hxc + rbase + hadr[1]);
      const uint4 hv2 = *(const uint4*)(hxc + rbase + hadr[2]);
      const uint4 hv3 = *(const uint4*)(hxc + rbase + hadr[3]);

      float G0, G1, G2, G3;
      GROUP(0, G0); GROUP(1, G1); GROUP(2, G2); GROUP(3, G3);
      G0 = dpp_add<0x124>(G0); G1 = dpp_add<0x124>(G1);
      G2 = dpp_add<0x124>(G2); G3 = dpp_add<0x124>(G3);
      float r0 = b2 ? G1 : G0, r1 = b2 ? G3 : G2;
      r0 = dpp_add<0x128>(r0); r1 = dpp_add<0x128>(r1);
      const float red = b3 ? r1 : r0;

      // pre-activation q from pcur4 (selects only)
      const u32 wlo  = (q & 4) ? pcur4.z : pcur4.x;
      const u32 whi  = (q & 4) ? pcur4.w : pcur4.y;
      const u32 wsel = (q & 2) ? whi : wlo;
      const u16 pq   = (u16)((q & 1) ? (wsel >> 16) : (wsel & 0xffffu));

      const float h = fast_tanh(red + bias + (float)__builtin_bit_cast(_Float16, pq));
      hlast = h;
      const u16 h16 = __builtin_bit_cast(u16, (_Float16)h);
      *(u16*)(hxc + wbase + waddr) = h16;

      if (isL0) {
        u32 v = (u32)h16;
        u32 nb = dpp_mov_u32<0xB1>(v);
        if (!(tid & 1))
          st_sc01(&o0p[(size_t)t * 256 + (tid >> 1)], v | (nb << 16));
      }

      if (q == 7) { VM_DRAIN(); __syncthreads(); }  // drain sc01 stores for flag
      else        lds_barrier();                    // LDS-only ordering
    }

    if (isL0 && tid == 0) st_sc01(flagOut0, (u32)(c * 8 + 8));

    // rotate chunk buffers, prefetch chunk c+2 (IC-direct)
    pcur4 = pnext4;
    if (c < TSEQ / 8 - 2) {
      const int c2 = c + 2;
      const u32 need = (u32)(8 * (c2 + 1));
      if (isL0) {
        if (c2 < 128) { spin_sc01(f0, need, s0); }
        else          { spin_sc01(f1, need - 1024u, s1); }
      } else {
        const int w = c2 & 3;
        if      (w == 0) { spin_sc01(fpA, need, sA); }
        else if (w == 1) { spin_sc01(fpB, need, sB); }
        else if (w == 2) { spin_sc01(fpC, need, sC); }
        else             { spin_sc01(fpD, need, sD); }
      }
      pnext4 = ld1x4_sc01(&pin4[(size_t)c2 * 512 + tid]);
    }
  }
#undef GROUP
#undef ROW16

  if (!isL0) h1f[(size_t)b * NH + tid] = hlast;  // kernel boundary flushes
}

__global__ void fc_kernel(const float* __restrict__ h1f, const float* __restrict__ Wfc,
                          const float* __restrict__ bfc, float* __restrict__ out) {
  const int b = blockIdx.x, o = threadIdx.x;  // 20 blocks x 128 threads
  __shared__ float hs[NH];
  for (int i = o; i < NH; i += NOUT) hs[i] = h1f[(size_t)b * NH + i];
  __syncthreads();
  const float4* w4 = (const float4*)(Wfc + (size_t)o * NH);
  const float4* h4 = (const float4*)hs;
  float acc = bfc[o];
#pragma unroll 8
  for (int j = 0; j < NH / 4; j++) {
    float4 w = w4[j], h = h4[j];
    acc += w.x * h.x + w.y * h.y + w.z * h.z + w.w * h.w;
  }
  out[(size_t)b * NOUT + o] = acc;
}

extern "C" void kernel_launch(void* const* d_in, const int* in_sizes, int n_in,
                              void* d_out, int out_size, void* d_ws, size_t ws_size,
                              hipStream_t stream) {
  const float* x    = (const float*)d_in[0];
  const float* h0   = (const float*)d_in[1];
  const float* Wih0 = (const float*)d_in[2];
  const float* Whh0 = (const float*)d_in[3];
  const float* bih0 = (const float*)d_in[4];
  const float* bhh0 = (const float*)d_in[5];
  const float* Wih1 = (const float*)d_in[6];
  const float* Whh1 = (const float*)d_in[7];
  const float* bih1 = (const float*)d_in[8];
  const float* bhh1 = (const float*)d_in[9];
  const float* Wfc  = (const float*)d_in[10];
  const float* bfc  = (const float*)d_in[11];
  float* out = (float*)d_out;

  char* ws = (char*)d_ws;
  size_t off = 0;
  u16* pre0 = (u16*)(ws + off); off += (size_t)NB * TSEQ * NH * 2;
  u32* out0 = (u32*)(ws + off); off += (size_t)NB * TSEQ * (NH / 2) * 4;
  u16* pre1 = (u16*)(ws + off); off += (size_t)NB * TSEQ * NH * 2;
  float* h1f = (float*)(ws + off); off += (size_t)NB * NH * 4;
  int* flags = (int*)(ws + off);
  const size_t flagbytes = FLAG_LINES * 32 * sizeof(int);
  off += flagbytes;
  u32* gw = (u32*)(ws + off);                       // 2 x 128 KB weight slabs

  (void)hipMemsetAsync(flags, 0, flagbytes, stream);
  (void)hipFuncSetAttribute((const void*)rnn_persist,
                            hipFuncAttributeMaxDynamicSharedMemorySize, SMEM_BYTES);
  rnn_persist<<<160, 512, SMEM_BYTES, stream>>>(
      x, h0, Wih0, Whh0, bih0, bhh0, Wih1, Whh1, bih1, bhh1,
      pre0, out0, pre1, h1f, flags, gw);
  fc_kernel<<<NB, NOUT, 0, stream>>>(h1f, Wfc, bfc, out);
}

// Round 14
// 3647.137 us; speedup vs baseline: 6.7467x; 1.8082x over previous
//
#include <hip/hip_runtime.h>

#define TSEQ 2048
#define NB   20
#define NIN  256
#define NH   512
#define NOUT 128

typedef unsigned int   u32;
typedef unsigned short u16;
typedef _Float16 f16x2 __attribute__((ext_vector_type(2)));

// dynamic LDS layout
#define SM_W     0                 // 131072 B: WLw uint4[16][512] (recurrence) / WL uint2[32][512] (pre1)
#define SM_HX    131072            // 2048 B: h exchange, TWO sigma-swizzled f16[512] buffers
#define SM_INP   (131072 + 2048)   // 2048 B: u32 [2][256] input staging (pre roles)
#define SMEM_BYTES (131072 + 2048 + 2048)

__device__ __forceinline__ u32 packh2(float a, float b) {
  f16x2 p; p.x = (_Float16)a; p.y = (_Float16)b;
  return __builtin_bit_cast(u32, p);
}

__device__ __forceinline__ float dot2(u32 w, u32 h, float acc) {
  return __builtin_amdgcn_fdot2(__builtin_bit_cast(f16x2, w),
                                __builtin_bit_cast(f16x2, h), acc, false);
}

__device__ __forceinline__ int acq(const int* p) {
  return __hip_atomic_load(p, __ATOMIC_ACQUIRE, __HIP_MEMORY_SCOPE_AGENT);
}
__device__ __forceinline__ void rel(int* p, int v) {
  __hip_atomic_store(p, v, __ATOMIC_RELEASE, __HIP_MEMORY_SCOPE_AGENT);
}
// spin with s_sleep backoff (outlier insurance, verified r7)
__device__ __forceinline__ void spin_until(const int* p, int need, int& seen) {
  while (seen < need) {
    seen = acq(p);
    if (seen < need) __builtin_amdgcn_s_sleep(1);
  }
}

// LDS-only barrier: orders LDS ops across the workgroup WITHOUT draining vmcnt
// (so in-flight global stores / prefetch loads stay in flight across steps).
__device__ __forceinline__ void lds_barrier() {
  asm volatile("s_waitcnt lgkmcnt(0)\n\ts_barrier" ::: "memory");
}

// cross-lane add via DPP (VALU pipe, no LDS).
// 0xB1 quad_perm[1,0,3,2]=xor1, 0x4E quad_perm[2,3,0,1]=xor2,
// 0x124 row_ror:4, 0x128 row_ror:8 (rows are 16 lanes on gfx9+)
template<int CTRL>
__device__ __forceinline__ float dpp_add(float x) {
  int v = __builtin_amdgcn_update_dpp(0, __builtin_bit_cast(int, x), CTRL, 0xF, 0xF, true);
  return x + __builtin_bit_cast(float, v);
}

template<int CTRL>
__device__ __forceinline__ u32 dpp_mov_u32(u32 x) {
  return (u32)__builtin_amdgcn_update_dpp(0, (int)x, CTRL, 0xF, 0xF, true);
}

__device__ __forceinline__ float fast_tanh(float x) {
  float xc = fminf(fmaxf(x, -15.f), 15.f);
  float e = __builtin_amdgcn_exp2f(xc * 2.8853900817779268f);  // exp(2x)
  return (e - 1.f) * __builtin_amdgcn_rcpf(e + 1.f);
}

// sigma-swizzle for hx (verified rounds 4-7: SQ_LDS_BANK_CONFLICT = 0)
__device__ __forceinline__ int hx_gran_off(int g, int c) {
  int pg = (g ^ (g >> 2)) & 15;
  return 64 * pg + 16 * (c ^ (g & 3));
}

// Persistent fused pipeline. grid = 160 blocks x 512 threads, 1 block/CU.
//  bid   0..39 : pre0 (b=bid>>1, half=bid&1)        pre0 = x@Wih0^T + bih0 (f16, 8-t tiles)
//  bid  40..59 : L0 recurrence (b=bid-40)           out0 = h packed f16 pairs
//  bid 60..139 : pre1 (b=(bid-60)>>2, sub=(bid-60)&3) 4-way t-chunked gather (8-t tiles)
//  bid140..159 : L1 recurrence (b=bid-140)          h1f = last h (f32)
//
// CHAMPION RESTORE (round-6 source, benched 3636us in round 7). Only delta:
// out0 pack+store hoisted above the hx LDS write (issue-order cosmetic).
__global__ __launch_bounds__(512, 2) void rnn_persist(
    const float* __restrict__ x,    const float* __restrict__ h0,
    const float* __restrict__ Wih0, const float* __restrict__ Whh0,
    const float* __restrict__ bih0, const float* __restrict__ bhh0,
    const float* __restrict__ Wih1, const float* __restrict__ Whh1,
    const float* __restrict__ bih1, const float* __restrict__ bhh1,
    u16* __restrict__ pre0, u32* __restrict__ out0,
    u16* __restrict__ pre1, float* __restrict__ h1f,
    int* __restrict__ flags)
{
  extern __shared__ char smem[];
  const int tid = threadIdx.x;
  const int bid = blockIdx.x;

  if (bid < 40) {
    // ---------------- pre0: x @ Wih0^T + bih0 (tiled store) ----------------
    u32* inp = (u32*)(smem + SM_INP);
    const int b = bid >> 1, half = bid & 1, t0 = half * 1024;
    const int n = tid;
    u32 wr[128];
    const float4* W4 = (const float4*)(Wih0 + (size_t)n * NIN);
#pragma unroll
    for (int j = 0; j < 64; j++) {
      float4 w = W4[j];
      wr[2*j] = packh2(w.x, w.y); wr[2*j+1] = packh2(w.z, w.w);
    }
    const float bias = bih0[n];
    const float* xb = x + ((size_t)b * TSEQ + t0) * NIN;
    u16* op = pre0 + ((size_t)b * TSEQ + t0) * NH;

    float2 r = make_float2(0.f, 0.f);
    if (tid < 128) r = ((const float2*)xb)[tid];
    int cur = 0;
    for (int t = 0; t < 1024; t++) {
      if (tid < 128) inp[cur * 256 + tid] = packh2(r.x, r.y);
      __syncthreads();
      if (t + 1 < 1024 && tid < 128)
        r = ((const float2*)(xb + (size_t)(t + 1) * NIN))[tid];
      float a0 = bias, a1 = 0.f;
      const uint4* xp = (const uint4*)(inp + cur * 256);
#pragma unroll
      for (int j = 0; j < 32; j++) {
        uint4 hv = xp[j];
        a0 = dot2(wr[4*j+0], hv.x, a0); a1 = dot2(wr[4*j+1], hv.y, a1);
        a0 = dot2(wr[4*j+2], hv.z, a0); a1 = dot2(wr[4*j+3], hv.w, a1);
      }
      op[((size_t)(t >> 3) * NH + n) * 8 + (t & 7)] =
          __builtin_bit_cast(u16, (_Float16)(a0 + a1));
      cur ^= 1;
      if (((t + 1) & 7) == 0) {
        __syncthreads();
        if (tid == 0) rel(flags + bid * 32, t + 1);
      }
    }
    return;
  }

  if (bid >= 60 && bid < 140) {
    // ---------------- pre1: out0 @ Wih1^T + bih1, 4-way t-chunk split ----------------
    uint2* WL  = (uint2*)(smem + SM_W);
    u32*   inp = (u32*)(smem + SM_INP);
    const int b = (bid - 60) >> 2, sub = (bid - 60) & 3;
    const int n = tid;
    u32 wr[192];
    const float4* W4 = (const float4*)(Wih1 + (size_t)n * NH);
#pragma unroll
    for (int j = 0; j < 96; j++) {
      float4 w = W4[j];
      wr[2*j] = packh2(w.x, w.y); wr[2*j+1] = packh2(w.z, w.w);
    }
#pragma unroll
    for (int j2 = 0; j2 < 32; j2++) {
      float4 w = W4[96 + j2];
      WL[j2 * NH + n] = make_uint2(packh2(w.x, w.y), packh2(w.z, w.w));
    }
    const float bias = bih1[n];
    __syncthreads();

    const u32* ip = out0 + (size_t)b * TSEQ * 256;
    u16* op = pre1 + (size_t)b * TSEQ * NH;
    const int* flagOut0 = flags + (40 + b) * 32;
    int* flagMy = flags + (60 + b * 4 + sub) * 32;
    int seen = 0, cur = 0;
#pragma unroll 1
    for (int c = sub; c < TSEQ / 8; c += 4) {
      const int tbase = c * 8;
      spin_until(flagOut0, tbase + 8, seen);
      u32 rin = (tid < 256) ? ip[(size_t)tbase * 256 + tid] : 0;
#pragma unroll 1
      for (int qq = 0; qq < 8; qq++) {
        const int t = tbase + qq;
        if (tid < 256) inp[cur * 256 + tid] = rin;
        __syncthreads();
        if (qq + 1 < 8 && tid < 256) rin = ip[(size_t)(t + 1) * 256 + tid];
        float a0 = bias, a1 = 0.f;
        const uint4* hp4 = (const uint4*)(inp + cur * 256);
#pragma unroll
        for (int j = 0; j < 48; j++) {
          uint4 hv = hp4[j];
          a0 = dot2(wr[4*j+0], hv.x, a0); a1 = dot2(wr[4*j+1], hv.y, a1);
          a0 = dot2(wr[4*j+2], hv.z, a0); a1 = dot2(wr[4*j+3], hv.w, a1);
        }
#pragma unroll
        for (int jj = 0; jj < 16; jj++) {
          uint4 hv = hp4[48 + jj];
          uint2 w0 = WL[(2*jj)   * NH + n];
          uint2 w1 = WL[(2*jj+1) * NH + n];
          a0 = dot2(w0.x, hv.x, a0); a1 = dot2(w0.y, hv.y, a1);
          a0 = dot2(w1.x, hv.z, a0); a1 = dot2(w1.y, hv.w, a1);
        }
        op[((size_t)(t >> 3) * NH + n) * 8 + (t & 7)] =
            __builtin_bit_cast(u16, (_Float16)(a0 + a1));
        cur ^= 1;
      }
      __syncthreads();
      if (tid == 0) rel(flagMy, tbase + 8);
    }
    return;
  }

  // ---------------- L0 / L1 recurrence: scatter + grouped DPP pairing tree ----------------
  const bool isL0 = (bid < 60);
  const int b = isL0 ? (bid - 40) : (bid - 140);
  const float* Wg = isL0 ? Whh0 : Whh1;
  const float* bp = isL0 ? bhh0 : bhh1;

  uint4* WLw4 = (uint4*)(smem + SM_W);  // slot s at (s*512 + tid), s = 0..15
  char*  hxc  = smem + SM_HX;           // 2x sigma-swizzled f16[512]

  const int lam = tid & 15;             // k-group: k in [32*lam, 32*lam+32)
  const int ns  = tid >> 4;             // n-slice: rows 16*ns .. 16*ns+15

  // Register rows: group g holds matrix rows 16*ns + {4g, 4g+1, 4g+2} in wj[3g+m].
  u32 wj[12][16];
#pragma unroll
  for (int g = 0; g < 4; g++) {
#pragma unroll
    for (int m = 0; m < 3; m++) {
      const float4* Wr = (const float4*)(Wg + (size_t)(16 * ns + 4 * g + m) * NH + 32 * lam);
#pragma unroll
      for (int k4 = 0; k4 < 8; k4++) {
        float4 w = Wr[k4];
        wj[3*g+m][2*k4] = packh2(w.x, w.y); wj[3*g+m][2*k4+1] = packh2(w.z, w.w);
      }
    }
  }
  // LDS rows: matrix row 16*ns + 4g+3 -> slots 4g + q (chunk q u32s).
#pragma unroll
  for (int g = 0; g < 4; g++) {
    const float4* Wr = (const float4*)(Wg + (size_t)(16 * ns + 4 * g + 3) * NH + 32 * lam);
#pragma unroll
    for (int q = 0; q < 4; q++) {
      float4 wA = Wr[2*q], wB = Wr[2*q+1];
      WLw4[(4 * g + q) * 512 + tid] =
          make_uint4(packh2(wA.x, wA.y), packh2(wA.z, wA.w),
                     packh2(wB.x, wB.y), packh2(wB.z, wB.w));
    }
  }
  const float bias = bp[tid];           // final owner n == tid

  // precomputed hx addresses (loop-invariant, static-indexed)
  int hadr[4];
#pragma unroll
  for (int c = 0; c < 4; c++) hadr[c] = hx_gran_off(lam, c);
  const int wg = (tid >> 5) & 15, wc = (tid >> 3) & 3;
  const int waddr = hx_gran_off(wg, wc) + (tid & 7) * 2;  // my h[tid] slot
  const bool b0 = (tid & 1), b1 = (tid & 2), b2 = (tid & 4), b3 = (tid & 8);

  // init h exchange buffer 0 with h0
  *(u16*)(hxc + waddr) =
      __builtin_bit_cast(u16, (_Float16)h0[((isL0 ? 0 : 1) * NB + b) * NH + tid]);
  __syncthreads();

  const uint4* pin4 =
      (const uint4*)((isL0 ? pre0 : pre1) + (size_t)b * TSEQ * NH);
  u32* o0p = out0 + (size_t)b * TSEQ * 256;
  int* flagOut0 = flags + (40 + b) * 32;
  const int* f0 = flags + (b * 2 + 0) * 32;       // pre0 halves (L0)
  const int* f1 = flags + (b * 2 + 1) * 32;
  const int* fpA = flags + (60 + b * 4 + 0) * 32; // pre1 subs (L1)
  const int* fpB = flags + (60 + b * 4 + 1) * 32;
  const int* fpC = flags + (60 + b * 4 + 2) * 32;
  const int* fpD = flags + (60 + b * 4 + 3) * 32;
  int s0 = 0, s1 = 0, sA = 0, sB = 0, sC = 0, sD = 0;

  // prologue: fetch chunk 0 into pcur4, chunk 1 into pnext4
  if (isL0) { spin_until(f0, 8, s0); }  else { spin_until(fpA, 8, sA); }
  uint4 pcur4 = pin4[tid];
  if (isL0) { spin_until(f0, 16, s0); } else { spin_until(fpB, 16, sB); }
  uint4 pnext4 = pin4[512 + tid];

  // group gi: rows 4gi..4gi+2 from wj[3gi..3gi+2], row 4gi+3 from LDS slots 4gi+q.
#define ROW16(acc, WR)                                              \
    acc = dot2(WR[0],  hv0.x, acc); acc = dot2(WR[1],  hv0.y, acc); \
    acc = dot2(WR[2],  hv0.z, acc); acc = dot2(WR[3],  hv0.w, acc); \
    acc = dot2(WR[4],  hv1.x, acc); acc = dot2(WR[5],  hv1.y, acc); \
    acc = dot2(WR[6],  hv1.z, acc); acc = dot2(WR[7],  hv1.w, acc); \
    acc = dot2(WR[8],  hv2.x, acc); acc = dot2(WR[9],  hv2.y, acc); \
    acc = dot2(WR[10], hv2.z, acc); acc = dot2(WR[11], hv2.w, acc); \
    acc = dot2(WR[12], hv3.x, acc); acc = dot2(WR[13], hv3.y, acc); \
    acc = dot2(WR[14], hv3.z, acc); acc = dot2(WR[15], hv3.w, acc)

#define GROUP(gi, OUT)                                               \
  {                                                                  \
    const uint4 wvA = WLw4[(4*gi + 0) * 512 + tid];                  \
    const uint4 wvB = WLw4[(4*gi + 1) * 512 + tid];                  \
    float a0 = 0.f, a1 = 0.f, a2 = 0.f, a3 = 0.f;                    \
    ROW16(a0, wj[3*gi+0]);                                           \
    a3 = dot2(wvA.x, hv0.x, a3); a3 = dot2(wvA.y, hv0.y, a3);        \
    a3 = dot2(wvA.z, hv0.z, a3); a3 = dot2(wvA.w, hv0.w, a3);        \
    const uint4 wvC = WLw4[(4*gi + 2) * 512 + tid];                  \
    const uint4 wvD = WLw4[(4*gi + 3) * 512 + tid];                  \
    ROW16(a1, wj[3*gi+1]);                                           \
    a3 = dot2(wvB.x, hv1.x, a3); a3 = dot2(wvB.y, hv1.y, a3);        \
    a3 = dot2(wvB.z, hv1.z, a3); a3 = dot2(wvB.w, hv1.w, a3);        \
    ROW16(a2, wj[3*gi+2]);                                           \
    a3 = dot2(wvC.x, hv2.x, a3); a3 = dot2(wvC.y, hv2.y, a3);        \
    a3 = dot2(wvC.z, hv2.z, a3); a3 = dot2(wvC.w, hv2.w, a3);        \
    a3 = dot2(wvD.x, hv3.x, a3); a3 = dot2(wvD.y, hv3.y, a3);        \
    a3 = dot2(wvD.z, hv3.z, a3); a3 = dot2(wvD.w, hv3.w, a3);        \
    float t0 = dpp_add<0xB1>(a0), t1 = dpp_add<0xB1>(a1);            \
    float t2 = dpp_add<0xB1>(a2), t3 = dpp_add<0xB1>(a3);            \
    float u0 = b0 ? t1 : t0, u1 = b0 ? t3 : t2;                      \
    u0 = dpp_add<0x4E>(u0); u1 = dpp_add<0x4E>(u1);                  \
    OUT = b1 ? u1 : u0;                                              \
  }

  float hlast = 0.f;
#pragma unroll 1
  for (int c = 0; c < TSEQ / 8; c++) {
#pragma unroll 1
    for (int q = 0; q < 8; q++) {
      const int t = c * 8 + q;
      const int rbase = (t & 1) << 10;   // read buffer
      const int wbase = rbase ^ 1024;    // write buffer

      const uint4 hv0 = *(const uint4*)(hxc + rbase + hadr[0]);
      const uint4 hv1 = *(const uint4*)(hxc + rbase + hadr[1]);
      const uint4 hv2 = *(const uint4*)(hxc + rbase + hadr[2]);
      const uint4 hv3 = *(const uint4*)(hxc + rbase + hadr[3]);

      float G0, G1, G2, G3;
      GROUP(0, G0); GROUP(1, G1); GROUP(2, G2); GROUP(3, G3);
      G0 = dpp_add<0x124>(G0); G1 = dpp_add<0x124>(G1);
      G2 = dpp_add<0x124>(G2); G3 = dpp_add<0x124>(G3);
      float r0 = b2 ? G1 : G0, r1 = b2 ? G3 : G2;
      r0 = dpp_add<0x128>(r0); r1 = dpp_add<0x128>(r1);
      const float red = b3 ? r1 : r0;

      // extract pre-activation q from pcur4 (selects only, no array indexing)
      const u32 wlo  = (q & 4) ? pcur4.z : pcur4.x;
      const u32 whi  = (q & 4) ? pcur4.w : pcur4.y;
      const u32 wsel = (q & 2) ? whi : wlo;
      const u16 pq   = (u16)((q & 1) ? (wsel >> 16) : (wsel & 0xffffu));

      const float h = fast_tanh(red + bias + (float)__builtin_bit_cast(_Float16, pq));
      hlast = h;
      const u16 h16 = __builtin_bit_cast(u16, (_Float16)h);

      if (isL0) {
        // pack (h[2k], h[2k+1]) via DPP xor1; issue the vmem store FIRST so it
        // overlaps the LDS write + barrier (drained at q==7 before flag release)
        u32 v = (u32)h16;
        u32 nb = dpp_mov_u32<0xB1>(v);
        if (!(tid & 1)) o0p[(size_t)t * 256 + (tid >> 1)] = v | (nb << 16);
      }
      *(u16*)(hxc + wbase + waddr) = h16;

      if (q == 7) __syncthreads();  // full drain (vm for flag release)
      else        lds_barrier();    // LDS-only ordering; vm ops stay in flight
    }

    if (isL0 && tid == 0) rel(flagOut0, c * 8 + 8);

    // rotate chunk buffers, prefetch chunk c+2
    pcur4 = pnext4;
    if (c < TSEQ / 8 - 2) {
      const int c2 = c + 2;
      const int need = 8 * (c2 + 1);
      if (isL0) {
        if (c2 < 128) { spin_until(f0, need, s0); }
        else          { spin_until(f1, need - 1024, s1); }
      } else {
        const int w = c2 & 3;
        if      (w == 0) { spin_until(fpA, need, sA); }
        else if (w == 1) { spin_until(fpB, need, sB); }
        else if (w == 2) { spin_until(fpC, need, sC); }
        else             { spin_until(fpD, need, sD); }
      }
      pnext4 = pin4[(size_t)c2 * 512 + tid];
    }
  }
#undef GROUP
#undef ROW16

  if (!isL0) h1f[(size_t)b * NH + tid] = hlast;
}

__global__ void fc_kernel(const float* __restrict__ h1f, const float* __restrict__ Wfc,
                          const float* __restrict__ bfc, float* __restrict__ out) {
  const int b = blockIdx.x, o = threadIdx.x;  // 20 blocks x 128 threads
  __shared__ float hs[NH];
  for (int i = o; i < NH; i += NOUT) hs[i] = h1f[(size_t)b * NH + i];
  __syncthreads();
  const float4* w4 = (const float4*)(Wfc + (size_t)o * NH);
  const float4* h4 = (const float4*)hs;
  float acc = bfc[o];
#pragma unroll 8
  for (int j = 0; j < NH / 4; j++) {
    float4 w = w4[j], h = h4[j];
    acc += w.x * h.x + w.y * h.y + w.z * h.z + w.w * h.w;
  }
  out[(size_t)b * NOUT + o] = acc;
}

extern "C" void kernel_launch(void* const* d_in, const int* in_sizes, int n_in,
                              void* d_out, int out_size, void* d_ws, size_t ws_size,
                              hipStream_t stream) {
  const float* x    = (const float*)d_in[0];
  const float* h0   = (const float*)d_in[1];
  const float* Wih0 = (const float*)d_in[2];
  const float* Whh0 = (const float*)d_in[3];
  const float* bih0 = (const float*)d_in[4];
  const float* bhh0 = (const float*)d_in[5];
  const float* Wih1 = (const float*)d_in[6];
  const float* Whh1 = (const float*)d_in[7];
  const float* bih1 = (const float*)d_in[8];
  const float* bhh1 = (const float*)d_in[9];
  const float* Wfc  = (const float*)d_in[10];
  const float* bfc  = (const float*)d_in[11];
  float* out = (float*)d_out;

  char* ws = (char*)d_ws;
  size_t off = 0;
  u16* pre0 = (u16*)(ws + off); off += (size_t)NB * TSEQ * NH * 2;
  u32* out0 = (u32*)(ws + off); off += (size_t)NB * TSEQ * (NH / 2) * 4;
  u16* pre1 = (u16*)(ws + off); off += (size_t)NB * TSEQ * NH * 2;
  float* h1f = (float*)(ws + off); off += (size_t)NB * NH * 4;
  int* flags = (int*)(ws + off);
  const size_t flagbytes = 160 * 32 * sizeof(int);

  (void)hipMemsetAsync(flags, 0, flagbytes, stream);
  (void)hipFuncSetAttribute((const void*)rnn_persist,
                            hipFuncAttributeMaxDynamicSharedMemorySize, SMEM_BYTES);
  rnn_persist<<<160, 512, SMEM_BYTES, stream>>>(
      x, h0, Wih0, Whh0, bih0, bhh0, Wih1, Whh1, bih1, bhh1,
      pre0, out0, pre1, h1f, flags);
  fc_kernel<<<NB, NOUT, 0, stream>>>(h1f, Wfc, bfc, out);
}